// Round 11
// baseline (113.434 us; speedup 1.0000x reference)
//
#include <hip/hip_runtime.h>
#include <hip/hip_bf16.h>
#include <cstdint>
#include <cstddef>

// Problem dims (fixed): B=4, NI=NO=256, DIN=DQ=DH=DOUT=256.
// out[b,i,j,:] = gelu(u[b,i,:] + v[b,j,:]) @ W2 + b2
//   u = (x@W_pre + b_pre)@W1[:256] + b1   (b1 folded into u)
//   v = (query@W_emb + b_emb)@W1[256:]

typedef __bf16  bf16x8 __attribute__((ext_vector_type(8)));
typedef float   f32x16 __attribute__((ext_vector_type(16)));

// tanh-approx gelu with exp2 constant pre-folded:
// gelu(x) ~= x / (1 + exp2(x*(-2.3022072 - 0.1029433*x^2)))
__device__ __forceinline__ float fast_gelu(float x) {
    const float x2 = x * x;
    const float m  = __builtin_fmaf(x2, -0.1029433f, -2.3022072f);
    const float e  = __builtin_amdgcn_exp2f(x * m);
    return x * __builtin_amdgcn_rcpf(1.0f + e);
}

// ---------------------------------------------------------------------------
// Prep kernel (one launch) — unchanged from round 8 (passed, ~10 us).
// ---------------------------------------------------------------------------
__global__ __launch_bounds__(256) void prep_kernel(
    const float* __restrict__ x, const float* __restrict__ query,
    const float* __restrict__ W_pre, const float* __restrict__ b_pre,
    const float* __restrict__ W_emb, const float* __restrict__ b_emb,
    const float* __restrict__ W1, const float* __restrict__ b1,
    const float* __restrict__ W2,
    float* __restrict__ u, float* __restrict__ v,
    unsigned short* __restrict__ w2t)
{
    const int b = blockIdx.x;
    const int t = threadIdx.x;

    if (b >= 512) {                       // W2 transpose + bf16 convert
        const int n0 = (b - 512) * 4;
        const float4 wv = *reinterpret_cast<const float4*>(W2 + (size_t)t * 256 + n0);
        const float vals[4] = {wv.x, wv.y, wv.z, wv.w};
#pragma unroll
        for (int j = 0; j < 4; ++j) {
            const __bf16 bv = (__bf16)vals[j];
            w2t[(size_t)(n0 + j) * 256 + t] = __builtin_bit_cast(unsigned short, bv);
        }
        return;
    }

    const bool isq = (b >= 256);
    const float* __restrict__ A   = isq ? query : x;
    const float* __restrict__ Wa  = isq ? W_emb : W_pre;
    const float* __restrict__ ba  = isq ? b_emb : b_pre;
    const float* __restrict__ W1p = isq ? (W1 + 256 * 256) : W1;
    float* __restrict__ outp      = isq ? v : u;
    const int r0 = (isq ? (b - 256) : b) * 4;

    __shared__ float as[4][256];
    __shared__ float xs[4][256];

#pragma unroll
    for (int r = 0; r < 4; ++r)
        as[r][t] = A[(size_t)(r0 + r) * 256 + t];
    __syncthreads();

    float acc[4] = {0.f, 0.f, 0.f, 0.f};
    {
        float wcur[8];
#pragma unroll
        for (int q = 0; q < 8; ++q) wcur[q] = Wa[(size_t)q * 256 + t];
        for (int k0 = 0; k0 < 248; k0 += 8) {
            float wnxt[8];
#pragma unroll
            for (int q = 0; q < 8; ++q)
                wnxt[q] = Wa[(size_t)(k0 + 8 + q) * 256 + t];
#pragma unroll
            for (int q = 0; q < 8; ++q)
#pragma unroll
                for (int r = 0; r < 4; ++r)
                    acc[r] = __builtin_fmaf(as[r][k0 + q], wcur[q], acc[r]);
#pragma unroll
            for (int q = 0; q < 8; ++q) wcur[q] = wnxt[q];
        }
#pragma unroll
        for (int q = 0; q < 8; ++q)
#pragma unroll
            for (int r = 0; r < 4; ++r)
                acc[r] = __builtin_fmaf(as[r][248 + q], wcur[q], acc[r]);
    }
    const float bav = ba[t];
#pragma unroll
    for (int r = 0; r < 4; ++r) xs[r][t] = acc[r] + bav;
    __syncthreads();

    float acc2[4] = {0.f, 0.f, 0.f, 0.f};
    {
        float wcur[8];
#pragma unroll
        for (int q = 0; q < 8; ++q) wcur[q] = W1p[(size_t)q * 256 + t];
        for (int k0 = 0; k0 < 248; k0 += 8) {
            float wnxt[8];
#pragma unroll
            for (int q = 0; q < 8; ++q)
                wnxt[q] = W1p[(size_t)(k0 + 8 + q) * 256 + t];
#pragma unroll
            for (int q = 0; q < 8; ++q)
#pragma unroll
                for (int r = 0; r < 4; ++r)
                    acc2[r] = __builtin_fmaf(xs[r][k0 + q], wcur[q], acc2[r]);
#pragma unroll
            for (int q = 0; q < 8; ++q) wcur[q] = wnxt[q];
        }
#pragma unroll
        for (int q = 0; q < 8; ++q)
#pragma unroll
            for (int r = 0; r < 4; ++r)
                acc2[r] = __builtin_fmaf(xs[r][248 + q], wcur[q], acc2[r]);
    }
    const float b1v = isq ? 0.f : b1[t];
#pragma unroll
    for (int r = 0; r < 4; ++r)
        outp[(size_t)(r0 + r) * 256 + t] = acc2[r] + b1v;
}

// ---------------------------------------------------------------------------
// Fused main kernel — W2T col-half staged ONCE; 2-phase K-loop; lean VGPR.
//
// Block = 512 thr = 8 waves; tile = 128 j-rows x 128 cols; grid 4096:
//   tile = bid>>2 (b,i), jh = (bid>>1)&1 (row half), ch = bid&1 (col half).
// Wave w: wr = w>>1 (rows wr*32..+32), wc = w&1 (cols wc*64..+64).
// acc = 2 x f32x16 = 32 VGPR -> total ~100 VGPR, fits (512,4)'s 128 cap.
// LDS = W2T col-half [128 n][256 k] 64 KB (staged once, global_load_lds w16,
// linear dest + inverse-swizzled source granule) + H chunk [128 r][64 k]
// 16 KB = 80 KB -> 2 blocks/CU = 16 waves/CU.
//
// K-loop per 64-chunk (2 short phases, 2 barriers, NO staging phase):
//   issue V/U loads for c+1 (early, VMEM); gelu+pack+swizzled ds_write H(c);
//   barrier; 4 k-steps x (1 A + 2 B b128 reads, 2 MFMA); barrier.
// Shorter phases + once-staging remove the per-chunk vmcnt drain and give
// the 2 resident blocks finer-grained material to overlap pipes.
//
// mfma_f32_32x32x16_bf16 layouts (gfx950):
//   A: lane l holds A[l&31][(l>>5)*8 + e]
//   B: lane l holds B[(l>>5)*8 + e][l&31]
//   D: lane l reg r holds D[(r&3) + 8*(r>>2) + 4*(l>>5)][l&31]
// ---------------------------------------------------------------------------
__global__ __launch_bounds__(512, 4) void fused_kernel(
    const float* __restrict__ U, const float* __restrict__ V,
    const unsigned short* __restrict__ W2T, const float* __restrict__ b2,
    float* __restrict__ out)
{
    __shared__ uint4 wlds[4096];   // 64 KB: W2T col-half [128 n][32 g], swizzled
    __shared__ uint4 hlds[1024];   // 16 KB: H chunk [128 r][8 g], swizzled
    unsigned int* const h32 = reinterpret_cast<unsigned int*>(hlds);

    const int t    = threadIdx.x;
    const int lane = t & 63;
    const int w    = t >> 6;       // 0..7
    const int l31  = lane & 31;
    const int hi   = lane >> 5;    // 0..1
    const int wr   = w >> 1;       // 0..3 row-group (32 rows)
    const int wc   = w & 1;        // 0..1 col-group (64 cols)

    const int bid  = blockIdx.x;
    const int tile = bid >> 2;     // 0..1023 = (bb, ii)
    const int jh   = (bid >> 1) & 1;
    const int ch   = bid & 1;
    const int bb   = tile >> 8;
    const int n0   = ch * 128;     // global col base
    const int j0   = jh * 128;     // global row base (within 256 j's)

    // ---- stage W2T col-half ONCE (async, linear dest, pre-swizzled src) ----
#pragma unroll
    for (int it = 0; it < 8; ++it) {
        const int idx = it * 512 + t;          // linear LDS granule
        const int n   = idx >> 5;              // 0..127 local col
        const int gp  = idx & 31;              // LDS granule slot
        const int g   = (gp & 24) | ((gp ^ n) & 7);  // inverse-swizzled src
        __builtin_amdgcn_global_load_lds(
            (const __attribute__((address_space(1))) unsigned int*)
                (W2T + (size_t)(n0 + n) * 256 + g * 8),
            (__attribute__((address_space(3))) unsigned int*)(wlds + idx),
            16, 0, 0);
    }

    const float* __restrict__ urow  = U + (size_t)tile * 256;
    const float* __restrict__ vbase = V + ((size_t)(bb * 256 + j0)) * 256;

    // H-compute mapping: d = k-pair (k = kk+2d, 2d+1); rows rb + 16*p.
    const int d  = t & 31;
    const int rb = t >> 5;         // 0..15

    // hoist b2
    float bv[2];
#pragma unroll
    for (int cg = 0; cg < 2; ++cg) bv[cg] = b2[n0 + wc * 64 + cg * 32 + l31];

    float2 vvA[8], vvB[8];
    float2 u2A, u2B;

    auto load_chunk = [&](int kk, float2& u2, float2 (&vv)[8]) {
        u2 = *reinterpret_cast<const float2*>(urow + kk + 2 * d);
#pragma unroll
        for (int p = 0; p < 8; ++p) {
            const int row = rb + p * 16;       // whole rows per wave-instr
            vv[p] = *reinterpret_cast<const float2*>(
                vbase + (size_t)row * 256 + kk + 2 * d);
        }
    };

    auto gelu_write = [&](const float2& u2, const float2 (&vv)[8]) {
#pragma unroll
        for (int p = 0; p < 8; ++p) {
            const int row = rb + p * 16;
            union { unsigned int u32; __bf16 h[2]; } pk;
            pk.h[0] = (__bf16)fast_gelu(u2.x + vv[p].x);
            pk.h[1] = (__bf16)fast_gelu(u2.y + vv[p].y);
            h32[row * 32 + (((d >> 2) ^ (row & 7)) << 2) + (d & 3)] = pk.u32;
        }
    };

    f32x16 acc[2];
#pragma unroll
    for (int i = 0; i < 2; ++i) acc[i] = (f32x16)0.f;

    auto mfma_chunk = [&](int kk) {
        const int kg0 = kk >> 3;               // global granule base
#pragma unroll
        for (int s = 0; s < 4; ++s) {
            const int gl   = 2 * s + hi;       // local H granule 0..7
            const int arow = wr * 32 + l31;
            const bf16x8 afrag = __builtin_bit_cast(
                bf16x8, hlds[arow * 8 + (gl ^ (arow & 7))]);
            const int gk = kg0 + gl;           // global granule 0..31
#pragma unroll
            for (int cg = 0; cg < 2; ++cg) {
                const int nloc = wc * 64 + cg * 32 + l31;
                const int slot = (gk & 24) | ((gk ^ nloc) & 7);
                const bf16x8 bfrag = __builtin_bit_cast(
                    bf16x8, wlds[nloc * 32 + slot]);
                acc[cg] = __builtin_amdgcn_mfma_f32_32x32x16_bf16(
                    afrag, bfrag, acc[cg], 0, 0, 0);
            }
        }
    };

    // prologue: V/U chunk 0 in flight alongside W2T staging
    load_chunk(0, u2A, vvA);
    __syncthreads();               // drains gll + our loads

    // ---- 2-phase K-loop, statically unrolled A/B sides (rule #20) ----
    // chunk 0
    load_chunk(64, u2B, vvB);
    gelu_write(u2A, vvA);
    __syncthreads();
    mfma_chunk(0);
    __syncthreads();
    // chunk 1
    load_chunk(128, u2A, vvA);
    gelu_write(u2B, vvB);
    __syncthreads();
    mfma_chunk(64);
    __syncthreads();
    // chunk 2
    load_chunk(192, u2B, vvB);
    gelu_write(u2A, vvA);
    __syncthreads();
    mfma_chunk(128);
    __syncthreads();
    // chunk 3
    gelu_write(u2B, vvB);
    __syncthreads();
    mfma_chunk(192);

    // ---- epilogue: out[row][col] = acc + b2[col], nontemporal ----
    const size_t obase = ((size_t)tile << 16) + (size_t)j0 * 256;
#pragma unroll
    for (int cg = 0; cg < 2; ++cg) {
        const int col = n0 + wc * 64 + cg * 32 + l31;
#pragma unroll
        for (int rr = 0; rr < 16; ++rr) {
            const int row = wr * 32 + 4 * hi + (rr & 3) + 8 * (rr >> 2);
            __builtin_nontemporal_store(acc[cg][rr] + bv[cg],
                                        out + obase + (size_t)row * 256 + col);
        }
    }
}

// ---------------------------------------------------------------------------
extern "C" void kernel_launch(void* const* d_in, const int* in_sizes, int n_in,
                              void* d_out, int out_size, void* d_ws, size_t ws_size,
                              hipStream_t stream)
{
    const float* x     = (const float*)d_in[0];
    const float* query = (const float*)d_in[1];
    const float* W_pre = (const float*)d_in[2];
    const float* b_pre = (const float*)d_in[3];
    const float* W_emb = (const float*)d_in[4];
    const float* b_emb = (const float*)d_in[5];
    const float* W1    = (const float*)d_in[6];
    const float* b1    = (const float*)d_in[7];
    const float* W2    = (const float*)d_in[8];
    const float* b2    = (const float*)d_in[9];
    float* out = (float*)d_out;

    char* ws = (char*)d_ws;
    float* u            = (float*)(ws);                          // 1 MB
    float* v            = (float*)(ws + (1 << 20));              // 1 MB
    unsigned short* w2t = (unsigned short*)(ws + 2 * (1 << 20)); // 128 KB

    prep_kernel<<<576, 256, 0, stream>>>(x, query, W_pre, b_pre, W_emb, b_emb,
                                         W1, b1, W2, u, v, w2t);
    fused_kernel<<<4096, 512, 0, stream>>>(u, v, w2t, b2, out);
}

// Round 12
// 99.062 us; speedup vs baseline: 1.1451x; 1.1451x over previous
//
#include <hip/hip_runtime.h>
#include <hip/hip_bf16.h>
#include <cstdint>
#include <cstddef>

// Problem dims (fixed): B=4, NI=NO=256, DIN=DQ=DH=DOUT=256.
// out[b,i,j,:] = gelu(u[b,i,:] + v[b,j,:]) @ W2 + b2
//   u = (x@W_pre + b_pre)@W1[:256] + b1   (b1 folded into u)
//   v = (query@W_emb + b_emb)@W1[256:]

typedef __bf16  bf16x8 __attribute__((ext_vector_type(8)));
typedef float   f32x16 __attribute__((ext_vector_type(16)));

// tanh-approx gelu with exp2 constant pre-folded:
// gelu(x) ~= x / (1 + exp2(x*(-2.3022072 - 0.1029433*x^2)))
__device__ __forceinline__ float fast_gelu(float x) {
    const float x2 = x * x;
    const float m  = __builtin_fmaf(x2, -0.1029433f, -2.3022072f);
    const float e  = __builtin_amdgcn_exp2f(x * m);
    return x * __builtin_amdgcn_rcpf(1.0f + e);
}

// ---------------------------------------------------------------------------
// Prep kernel (one launch) — unchanged from round 8 (passed, ~10 us).
// ---------------------------------------------------------------------------
__global__ __launch_bounds__(256) void prep_kernel(
    const float* __restrict__ x, const float* __restrict__ query,
    const float* __restrict__ W_pre, const float* __restrict__ b_pre,
    const float* __restrict__ W_emb, const float* __restrict__ b_emb,
    const float* __restrict__ W1, const float* __restrict__ b1,
    const float* __restrict__ W2,
    float* __restrict__ u, float* __restrict__ v,
    unsigned short* __restrict__ w2t)
{
    const int b = blockIdx.x;
    const int t = threadIdx.x;

    if (b >= 512) {                       // W2 transpose + bf16 convert
        const int n0 = (b - 512) * 4;
        const float4 wv = *reinterpret_cast<const float4*>(W2 + (size_t)t * 256 + n0);
        const float vals[4] = {wv.x, wv.y, wv.z, wv.w};
#pragma unroll
        for (int j = 0; j < 4; ++j) {
            const __bf16 bv = (__bf16)vals[j];
            w2t[(size_t)(n0 + j) * 256 + t] = __builtin_bit_cast(unsigned short, bv);
        }
        return;
    }

    const bool isq = (b >= 256);
    const float* __restrict__ A   = isq ? query : x;
    const float* __restrict__ Wa  = isq ? W_emb : W_pre;
    const float* __restrict__ ba  = isq ? b_emb : b_pre;
    const float* __restrict__ W1p = isq ? (W1 + 256 * 256) : W1;
    float* __restrict__ outp      = isq ? v : u;
    const int r0 = (isq ? (b - 256) : b) * 4;

    __shared__ float as[4][256];
    __shared__ float xs[4][256];

#pragma unroll
    for (int r = 0; r < 4; ++r)
        as[r][t] = A[(size_t)(r0 + r) * 256 + t];
    __syncthreads();

    float acc[4] = {0.f, 0.f, 0.f, 0.f};
    {
        float wcur[8];
#pragma unroll
        for (int q = 0; q < 8; ++q) wcur[q] = Wa[(size_t)q * 256 + t];
        for (int k0 = 0; k0 < 248; k0 += 8) {
            float wnxt[8];
#pragma unroll
            for (int q = 0; q < 8; ++q)
                wnxt[q] = Wa[(size_t)(k0 + 8 + q) * 256 + t];
#pragma unroll
            for (int q = 0; q < 8; ++q)
#pragma unroll
                for (int r = 0; r < 4; ++r)
                    acc[r] = __builtin_fmaf(as[r][k0 + q], wcur[q], acc[r]);
#pragma unroll
            for (int q = 0; q < 8; ++q) wcur[q] = wnxt[q];
        }
#pragma unroll
        for (int q = 0; q < 8; ++q)
#pragma unroll
            for (int r = 0; r < 4; ++r)
                acc[r] = __builtin_fmaf(as[r][248 + q], wcur[q], acc[r]);
    }
    const float bav = ba[t];
#pragma unroll
    for (int r = 0; r < 4; ++r) xs[r][t] = acc[r] + bav;
    __syncthreads();

    float acc2[4] = {0.f, 0.f, 0.f, 0.f};
    {
        float wcur[8];
#pragma unroll
        for (int q = 0; q < 8; ++q) wcur[q] = W1p[(size_t)q * 256 + t];
        for (int k0 = 0; k0 < 248; k0 += 8) {
            float wnxt[8];
#pragma unroll
            for (int q = 0; q < 8; ++q)
                wnxt[q] = W1p[(size_t)(k0 + 8 + q) * 256 + t];
#pragma unroll
            for (int q = 0; q < 8; ++q)
#pragma unroll
                for (int r = 0; r < 4; ++r)
                    acc2[r] = __builtin_fmaf(xs[r][k0 + q], wcur[q], acc2[r]);
#pragma unroll
            for (int q = 0; q < 8; ++q) wcur[q] = wnxt[q];
        }
#pragma unroll
        for (int q = 0; q < 8; ++q)
#pragma unroll
            for (int r = 0; r < 4; ++r)
                acc2[r] = __builtin_fmaf(xs[r][248 + q], wcur[q], acc2[r]);
    }
    const float b1v = isq ? 0.f : b1[t];
#pragma unroll
    for (int r = 0; r < 4; ++r)
        outp[(size_t)(r0 + r) * 256 + t] = acc2[r] + b1v;
}

// ---------------------------------------------------------------------------
// Fused main kernel — IDENTICAL to round 10 (best: 100.8 total) except the
// epilogue uses PLAIN stores (L2 write-back) instead of nontemporal.
// Single-variable A/B: R1 measured 1.6 TB/s effective write rate with nt
// stores while fillBuffer (plain stores) streams 6.9 TB/s. If the nt path
// is the write-rate limiter, this alone recovers ~15-20 us.
//
// Block = 512 threads = 8 waves (2 row-halves x 4 col-quarters); block tile
// = 128 j-rows x 256 cols; 2048 blocks. Wave (wr,wc) owns 64r x 64c:
// acc = 2x2 x f32x16 = 64 VGPR. LDS = W2T[256n][64k] 32 KB + H[128r][64k]
// 16 KB = 48 KB -> 2 blocks/CU = 16 waves/CU = 4 waves/SIMD.
//
// Per 64-k chunk (2 barriers):
//   stage W2T chunk via global_load_lds w16 (linear dest, inverse-swizzled
//   source granule, G21); H = gelu(u+v) coalesced (lane -> k-pair, 2 whole
//   rows per wave-instr; 2 passes of 4 rows), packed bf16x2 swizzled
//   ds_write; barrier; 4 k-steps x (2 A + 2 B b128 reads + 4 MFMA); barrier.
//
// mfma_f32_32x32x16_bf16 layouts (gfx950):
//   A: lane l holds A[l&31][(l>>5)*8 + e]
//   B: lane l holds B[(l>>5)*8 + e][l&31]
//   D: lane l reg r holds D[(r&3) + 8*(r>>2) + 4*(l>>5)][l&31]
// ---------------------------------------------------------------------------
__global__ __launch_bounds__(512, 4) void fused_kernel(
    const float* __restrict__ U, const float* __restrict__ V,
    const unsigned short* __restrict__ W2T, const float* __restrict__ b2,
    float* __restrict__ out)
{
    __shared__ uint4 wlds[2048];   // 32 KB: W2T chunk [256 n][8 g], swizzled
    __shared__ uint4 hlds[1024];   // 16 KB: H tile    [128 r][8 g], swizzled
    unsigned int* const h32 = reinterpret_cast<unsigned int*>(hlds);

    const int t    = threadIdx.x;
    const int lane = t & 63;
    const int w    = t >> 6;       // 0..7
    const int l31  = lane & 31;
    const int hi   = lane >> 5;    // 0..1
    const int wr   = w >> 2;       // 0..1 row-half (64 rows)
    const int wc   = w & 3;        // 0..3 col-quarter (64 cols)

    const size_t r0 = (size_t)blockIdx.x * 128;
    const int bb = (int)(r0 >> 16);
    const int ii = (int)((r0 >> 8) & 255);
    const int j0 = (int)(r0 & 255);          // 0 or 128

    const float* __restrict__ urow  = U + ((size_t)(bb * 256 + ii)) * 256;
    const float* __restrict__ vbase = V + ((size_t)(bb * 256 + j0)) * 256;

    // H-compute mapping: d = k-pair (k = kk+2d, 2d+1), rb = row base 0..15.
    const int d  = t & 31;
    const int rb = t >> 5;

    f32x16 acc[2][2];
#pragma unroll
    for (int rg = 0; rg < 2; ++rg)
#pragma unroll
        for (int cg = 0; cg < 2; ++cg) acc[rg][cg] = (f32x16)0.f;

    for (int kk = 0; kk < 256; kk += 64) {
        // ---- stage W2T chunk (async, linear dest, pre-swizzled source) ----
#pragma unroll
        for (int it = 0; it < 4; ++it) {
            const int idx = it * 512 + t;    // linear LDS granule
            const int n   = idx >> 3;        // 0..255
            const int gp  = idx & 7;         // LDS granule slot
            const int g   = gp ^ (n & 7);    // inverse-swizzled source granule
            __builtin_amdgcn_global_load_lds(
                (const __attribute__((address_space(1))) unsigned int*)
                    (W2T + (size_t)n * 256 + kk + g * 8),
                (__attribute__((address_space(3))) unsigned int*)(wlds + idx),
                16, 0, 0);
        }

        // ---- H tile: coalesced loads, gelu once, swizzled ds_write ----
        const float2 u2 = *reinterpret_cast<const float2*>(urow + kk + 2 * d);
#pragma unroll 1
        for (int pass = 0; pass < 2; ++pass) {   // 2 passes of 4 rows: VGPR cap
            float2 vv[4];
#pragma unroll
            for (int p = 0; p < 4; ++p) {
                const int row = rb + (pass * 4 + p) * 16;
                vv[p] = *reinterpret_cast<const float2*>(
                    vbase + (size_t)row * 256 + kk + 2 * d);
            }
#pragma unroll
            for (int p = 0; p < 4; ++p) {
                const int row = rb + (pass * 4 + p) * 16;
                union { unsigned int u32; __bf16 h[2]; } pk;
                pk.h[0] = (__bf16)fast_gelu(u2.x + vv[p].x);
                pk.h[1] = (__bf16)fast_gelu(u2.y + vv[p].y);
                h32[row * 32 + (((d >> 2) ^ (row & 7)) << 2) + (d & 3)] = pk.u32;
            }
        }
        __syncthreads();   // drains gll (vmcnt) + H writes

        // ---- MFMA: 4 k-steps, 2 A + 2 B reads per step ----
#pragma unroll
        for (int s = 0; s < 4; ++s) {
            const int gk = 2 * s + hi;       // k-granule within chunk
            bf16x8 af[2];
#pragma unroll
            for (int rg = 0; rg < 2; ++rg) {
                const int arow = wr * 64 + rg * 32 + l31;
                af[rg] = __builtin_bit_cast(
                    bf16x8, hlds[arow * 8 + (gk ^ (arow & 7))]);
            }
#pragma unroll
            for (int cg = 0; cg < 2; ++cg) {
                const int col = wc * 64 + cg * 32 + l31;
                const bf16x8 bf_ = __builtin_bit_cast(
                    bf16x8, wlds[col * 8 + (gk ^ (col & 7))]);
#pragma unroll
                for (int rg = 0; rg < 2; ++rg)
                    acc[rg][cg] = __builtin_amdgcn_mfma_f32_32x32x16_bf16(
                        af[rg], bf_, acc[rg][cg], 0, 0, 0);
            }
        }
        __syncthreads();
    }

    // ---- epilogue: out[row][col] = acc + b2[col], PLAIN stores (L2) ----
#pragma unroll
    for (int rg = 0; rg < 2; ++rg) {
#pragma unroll
        for (int cg = 0; cg < 2; ++cg) {
            const int col = wc * 64 + cg * 32 + l31;
            const float bv = b2[col];
#pragma unroll
            for (int rr = 0; rr < 16; ++rr) {
                const int row = wr * 64 + rg * 32 + 4 * hi + (rr & 3) + 8 * (rr >> 2);
                out[(r0 + row) * 256 + col] = acc[rg][cg][rr] + bv;
            }
        }
    }
}

// ---------------------------------------------------------------------------
extern "C" void kernel_launch(void* const* d_in, const int* in_sizes, int n_in,
                              void* d_out, int out_size, void* d_ws, size_t ws_size,
                              hipStream_t stream)
{
    const float* x     = (const float*)d_in[0];
    const float* query = (const float*)d_in[1];
    const float* W_pre = (const float*)d_in[2];
    const float* b_pre = (const float*)d_in[3];
    const float* W_emb = (const float*)d_in[4];
    const float* b_emb = (const float*)d_in[5];
    const float* W1    = (const float*)d_in[6];
    const float* b1    = (const float*)d_in[7];
    const float* W2    = (const float*)d_in[8];
    const float* b2    = (const float*)d_in[9];
    float* out = (float*)d_out;

    char* ws = (char*)d_ws;
    float* u            = (float*)(ws);                          // 1 MB
    float* v            = (float*)(ws + (1 << 20));              // 1 MB
    unsigned short* w2t = (unsigned short*)(ws + 2 * (1 << 20)); // 128 KB

    prep_kernel<<<576, 256, 0, stream>>>(x, query, W_pre, b_pre, W_emb, b_emb,
                                         W1, b1, W2, u, v, w2t);
    fused_kernel<<<2048, 512, 0, stream>>>(u, v, w2t, b2, out);
}